// Round 13
// baseline (210.023 us; speedup 1.0000x reference)
//
#include <hip/hip_runtime.h>
#include <math.h>

#define S 4096
#define CNUM 128
#define BATCH 4
#define MTOT (BATCH * S)
#define SCLOG2E 0.36067376022224085f   // 0.25 * log2(e): folded into Q at QKV epilogue
#define EPSLN 1e-5f
#define KSPLIT 8                        // k-range split for fused attn partials
#define QSPLIT 8                        // q-range split for column-sum pass

// All bf16 matrices ([row][128] or [row][256]) are stored as "swizzle images":
// element (row, col) lives at row*RL + ((col>>3 ^ (row&15))<<3) + (col&7).
// This is exactly the LDS layout every consumer kernel reads, so staging is a
// LINEAR global_load_lds DMA and all LDS-read code is unchanged.

typedef __attribute__((ext_vector_type(8))) short bf16x8;
typedef __attribute__((ext_vector_type(4))) float f32x4;
typedef __attribute__((ext_vector_type(16))) float f32x16;
typedef __attribute__((ext_vector_type(4))) unsigned int u32x4;

__device__ __forceinline__ float gelu_exact(float x) {
    return 0.5f * x * (1.0f + erff(x * 0.7071067811865476f));
}

__device__ __forceinline__ unsigned short f2b(float f) {
    union { float f; unsigned int u; } v; v.f = f;
    unsigned int r = (v.u + 0x7FFFu + ((v.u >> 16) & 1u)) >> 16;
    return (unsigned short)r;
}
__device__ __forceinline__ float b2f(unsigned short u) {
    return __uint_as_float((unsigned)u << 16);
}
// swizzled column offset within a row of an image matrix
__device__ __forceinline__ int swz(int col, int row) {
    return ((((col >> 3) ^ (row & 15)) << 3) | (col & 7));
}

// async 16B global->LDS (direct DMA, no VGPR round trip)
__device__ __forceinline__ void gl_lds16(const void* g, void* l) {
    __builtin_amdgcn_global_load_lds(
        (__attribute__((address_space(1))) void*)g,
        (__attribute__((address_space(3))) void*)l, 16, 0, 0);
}

// ---------------- transpose [B,C,S] -> [B,S,C]: t fp32 (residual), xlh bf16 image ----------------
__global__ __launch_bounds__(256) void ln1_transpose(
    const float* __restrict__ x, const float* __restrict__ w, const float* __restrict__ bb,
    unsigned short* __restrict__ xlh, float* __restrict__ t)
{
    __shared__ float tile[128][65];
    __shared__ float mu[64], rs[64];
    const int b = blockIdx.y;
    const int s0 = blockIdx.x * 64;
    const float* xb = x + (size_t)b * CNUM * S;
    for (int i = threadIdx.x; i < 128 * 64; i += 256) {
        int c = i >> 6, sl = i & 63;
        tile[c][sl] = xb[(size_t)c * S + s0 + sl];
    }
    __syncthreads();
    if (threadIdx.x < 64) {
        float sum = 0.f, sq = 0.f;
        for (int c = 0; c < 128; ++c) {
            float v = tile[c][threadIdx.x];
            sum += v; sq += v * v;
        }
        float m = sum * (1.f / 128.f);
        float var = sq * (1.f / 128.f) - m * m;
        mu[threadIdx.x] = m;
        rs[threadIdx.x] = rsqrtf(var + EPSLN);
    }
    __syncthreads();
    for (int i = threadIdx.x; i < 128 * 64; i += 256) {
        int c = i & 127, sl = i >> 7;
        float v = tile[c][sl];
        size_t row = (size_t)b * S + s0 + sl;
        t[row * CNUM + c] = v;
        xlh[row * CNUM + swz(c, sl)] = f2b((v - mu[sl]) * rs[sl] * w[c] + bb[c]);
    }
}

// ---------------- weight convert+transpose fp32[K,N] -> bf16 image [N][K]; biases packed ----------------
__global__ __launch_bounds__(256) void convw(
    const float* __restrict__ wq, const float* __restrict__ wk, const float* __restrict__ wv,
    const float* __restrict__ wo, const float* __restrict__ w1, const float* __restrict__ w2,
    const float* __restrict__ bq, const float* __restrict__ bk, const float* __restrict__ bv,
    unsigned short* __restrict__ wqkvh, unsigned short* __restrict__ woh,
    unsigned short* __restrict__ w1h, unsigned short* __restrict__ w2h,
    float* __restrict__ bqkv)
{
    int a = blockIdx.y;
    int idx = blockIdx.x * 256 + threadIdx.x;
    if (a == 6) {
        if (idx < 128) bqkv[idx] = bq[idx];
        else if (idx < 256) bqkv[idx] = bk[idx - 128];
        else if (idx < 384) bqkv[idx] = bv[idx - 256];
        return;
    }
    const float* src; unsigned short* dst; int Nsh, Ksz;
    switch (a) {
        case 0: src = wq; dst = wqkvh;          Nsh = 7; Ksz = 128; break;
        case 1: src = wk; dst = wqkvh + 16384;  Nsh = 7; Ksz = 128; break;
        case 2: src = wv; dst = wqkvh + 32768;  Nsh = 7; Ksz = 128; break;
        case 3: src = wo; dst = woh;            Nsh = 7; Ksz = 128; break;
        case 4: src = w1; dst = w1h;            Nsh = 8; Ksz = 128; break;
        default: src = w2; dst = w2h;           Nsh = 7; Ksz = 256; break;
    }
    int total = Ksz << Nsh;
    if (idx >= total) return;
    int k = idx >> Nsh, n = idx & ((1 << Nsh) - 1);
    dst[n * Ksz + swz(k, n)] = f2b(src[idx]);
}

// ---------------- MFMA GEMM: C = A[M,KT](image) @ Bt[N,KT]^T(image) + bias ----------------
// BM = M-tile (32: 4 waves x 32x32 each — 2x grid/occupancy vs 64).
// KT=256 stages B in two 128-k phases (Bs 32KB not 64KB) — k-ascending, bitwise-identical.
// EPI: 3 = A is KSPLIT part-slices (LINEAR) summed during staging; fp32 +res -> y AND LN2 -> zh image
//      6 = gelu -> bf16 image
//      7 = QKV (z=0: Q image scaled by SCLOG2E; z=1: K image; z=2: V chunk image)
//      8 = gelu + res -> fp32 out[b][col][s]
template<int KT, int EPI, int BM>
__global__ __launch_bounds__(256) void gemm_mfma(
    const unsigned short* __restrict__ A, const unsigned short* __restrict__ Bt,
    const float* __restrict__ bias, const float* __restrict__ res,
    void* __restrict__ Cv, void* __restrict__ Cv2,
    const float* __restrict__ wln, const float* __restrict__ bln, int N)
{
    constexpr int CH = KT / 8;
    constexpr int CSH = (KT == 128) ? 4 : 5;
    constexpr int BKT = (KT == 256) ? 128 : KT;    // B-stage K-phase width
    constexpr int NPH = KT / BKT;
    constexpr int NJ = (BM == 64) ? 4 : 2;         // N-frags per wave
    constexpr int NG = 128 / (NJ * 16);            // column groups (EPI3 LN)
    __shared__ unsigned short As[BM * KT];
    __shared__ unsigned short Bs[128 * BKT];
    __shared__ float2 lnred[(EPI == 3) ? NG * BM : 1];
    const int bm = blockIdx.y * BM;
    const int bn = blockIdx.x * 128;
    const int z = blockIdx.z;
    const unsigned short* Btz = (EPI == 7) ? Bt + z * 16384 : Bt;
    const float* biasz = (EPI == 7) ? bias + z * 128 : bias;
    const int tid = threadIdx.x;
    const int w = tid >> 6, l = tid & 63;
    const int rw = (BM == 64) ? (w & 1) * 32 : 0;
    const int cw = (BM == 64) ? (w >> 1) * 64 : w * 32;
    const int lm = l & 15, lq = l >> 4;

    f32x4 zero = {0.f, 0.f, 0.f, 0.f};
    f32x4 acc[2][NJ];
    #pragma unroll
    for (int i = 0; i < 2; ++i)
        #pragma unroll
        for (int j = 0; j < NJ; ++j) acc[i][j] = zero;

    #pragma unroll
    for (int ph = 0; ph < NPH; ++ph) {
        if (ph == 0) {
            if (EPI == 3) {
                // A-stage fused with the KSPLIT-partial reduction (parts is LINEAR layout)
                #pragma unroll
                for (int i = 0; i < (BM * CH) / 256; ++i) {
                    int cid = i * 256 + tid;
                    int r = cid >> CSH, c = cid & (CH - 1);
                    int p = (c & ~15) | ((c ^ r) & 15);
                    float s8[8];
                    #pragma unroll
                    for (int j = 0; j < 8; ++j) s8[j] = 0.f;
                    #pragma unroll
                    for (int pp = 0; pp < KSPLIT; ++pp) {
                        const unsigned short* src = A + (size_t)pp * ((size_t)MTOT * CNUM)
                                                      + (size_t)(bm + r) * KT + c * 8;
                        ushort4 u0 = *(const ushort4*)(src);
                        ushort4 u1 = *(const ushort4*)(src + 4);
                        s8[0] += b2f(u0.x); s8[1] += b2f(u0.y); s8[2] += b2f(u0.z); s8[3] += b2f(u0.w);
                        s8[4] += b2f(u1.x); s8[5] += b2f(u1.y); s8[6] += b2f(u1.z); s8[7] += b2f(u1.w);
                    }
                    ushort4 o0, o1;
                    o0.x = f2b(s8[0]); o0.y = f2b(s8[1]); o0.z = f2b(s8[2]); o0.w = f2b(s8[3]);
                    o1.x = f2b(s8[4]); o1.y = f2b(s8[5]); o1.z = f2b(s8[6]); o1.w = f2b(s8[7]);
                    *(ushort4*)(As + r * KT + p * 8) = o0;
                    *(ushort4*)(As + r * KT + p * 8 + 4) = o1;
                }
            } else {
                #pragma unroll
                for (int i = 0; i < (BM * CH) / 256; ++i)
                    gl_lds16(A + (size_t)bm * KT + (i * 256 + tid) * 8,
                             As + (i * 256 + tid) * 8);
            }
        } else {
            __syncthreads();   // previous phase's Bs readers done
        }
        // stage B phase ph: rows' [ph*BKT, +BKT) halves (contiguous 16B granules per row)
        #pragma unroll
        for (int i = 0; i < (128 * BKT / 8) / 256; ++i) {
            int cid = i * 256 + tid;
            int n = cid >> (CSH - (NPH - 1)), gg = cid & (BKT / 8 - 1);
            gl_lds16(Btz + (size_t)(bn + n) * KT + ph * BKT + gg * 8,
                     Bs + cid * 8);
        }
        __syncthreads();

        #pragma unroll
        for (int ks = 0; ks < BKT / 32; ++ks) {
            int c_loc = ks * 4 + lq;               // slot within phase (0..15)
            int c_glob = ph * 16 + c_loc;          // slot within full K row
            bf16x8 a[2], bfr[NJ];
            #pragma unroll
            for (int i = 0; i < 2; ++i) {
                int m = rw + i * 16 + lm;
                int p = (c_glob & ~15) | ((c_glob ^ m) & 15);
                a[i] = *(const bf16x8*)(As + m * KT + p * 8);
            }
            #pragma unroll
            for (int j = 0; j < NJ; ++j) {
                int n = cw + j * 16 + lm;
                int p = (c_loc ^ n) & 15;
                bfr[j] = *(const bf16x8*)(Bs + n * BKT + p * 8);
            }
            #pragma unroll
            for (int i = 0; i < 2; ++i)
                #pragma unroll
                for (int j = 0; j < NJ; ++j)
                    acc[i][j] = __builtin_amdgcn_mfma_f32_16x16x32_bf16(a[i], bfr[j], acc[i][j], 0, 0, 0);
        }
    }

    if (EPI == 3) {
        // y = acc + bias + res; then fused LN over the 128-col rows of this BM-row block.
        float vv[2][NJ][4];
        #pragma unroll
        for (int i = 0; i < 2; ++i) {
            int rowbase = bm + rw + i * 16 + lq * 4;
            #pragma unroll
            for (int j = 0; j < NJ; ++j) {
                int col = bn + cw + j * 16 + lm;
                #pragma unroll
                for (int reg = 0; reg < 4; ++reg)
                    vv[i][j][reg] = acc[i][j][reg] + biasz[col] +
                                    res[(size_t)(rowbase + reg) * N + col];
            }
        }
        #pragma unroll
        for (int i = 0; i < 2; ++i)
            #pragma unroll
            for (int reg = 0; reg < 4; ++reg) {
                float s = 0.f, q = 0.f;
                #pragma unroll
                for (int j = 0; j < NJ; ++j) {
                    float xv = vv[i][j][reg];
                    s += xv; q += xv * xv;
                }
                #pragma unroll
                for (int off = 1; off < 16; off <<= 1) {
                    s += __shfl_xor(s, off);
                    q += __shfl_xor(q, off);
                }
                if (lm == 0) {
                    float2 sq2; sq2.x = s; sq2.y = q;
                    lnred[(cw / (NJ * 16)) * BM + rw + i * 16 + lq * 4 + reg] = sq2;
                }
            }
        __syncthreads();
        #pragma unroll
        for (int i = 0; i < 2; ++i) {
            #pragma unroll
            for (int reg = 0; reg < 4; ++reg) {
                int lrow = rw + i * 16 + lq * 4 + reg;
                int row = bm + lrow;
                float sx = 0.f, sq = 0.f;
                #pragma unroll
                for (int g = 0; g < NG; ++g) {
                    float2 h = lnred[g * BM + lrow];
                    sx += h.x; sq += h.y;
                }
                float mean = sx * (1.f / 128.f);
                float var  = sq * (1.f / 128.f) - mean * mean;
                float rs = rsqrtf(var + EPSLN);
                #pragma unroll
                for (int j = 0; j < NJ; ++j) {
                    int col = bn + cw + j * 16 + lm;
                    float xv = vv[i][j][reg];
                    ((float*)Cv)[(size_t)row * N + col] = xv;
                    ((unsigned short*)Cv2)[(size_t)row * N + swz(col, lrow)] =
                        f2b((xv - mean) * rs * wln[col] + bln[col]);
                }
            }
        }
        return;
    }

    #pragma unroll
    for (int i = 0; i < 2; ++i) {
        int rowbase = bm + rw + i * 16 + lq * 4;
        #pragma unroll
        for (int j = 0; j < NJ; ++j) {
            int col = bn + cw + j * 16 + lm;
            float v[4];
            #pragma unroll
            for (int reg = 0; reg < 4; ++reg) v[reg] = acc[i][j][reg] + biasz[col];
            if (EPI == 6) {
                #pragma unroll
                for (int reg = 0; reg < 4; ++reg)
                    ((unsigned short*)Cv)[(size_t)(rowbase + reg) * N + swz(col, rowbase + reg)] =
                        f2b(gelu_exact(v[reg]));
            } else if (EPI == 8) {
                int bb = rowbase >> 12, s = rowbase & 4095;
                float4 o;
                o.x = gelu_exact(v[0]) + res[(size_t)(rowbase + 0) * N + col];
                o.y = gelu_exact(v[1]) + res[(size_t)(rowbase + 1) * N + col];
                o.z = gelu_exact(v[2]) + res[(size_t)(rowbase + 2) * N + col];
                o.w = gelu_exact(v[3]) + res[(size_t)(rowbase + 3) * N + col];
                *(float4*)(((float*)Cv) + ((size_t)(bb * 128 + col)) * 4096 + s) = o;
            } else if (EPI == 7) {
                if (z < 2) {
                    unsigned short* dst = ((unsigned short*)Cv) + (size_t)z * MTOT * 128;
                    #pragma unroll
                    for (int reg = 0; reg < 4; ++reg) {
                        float ov = (z == 0) ? v[reg] * SCLOG2E : v[reg];  // fold softmax scale into Q
                        dst[(size_t)(rowbase + reg) * 128 + swz(col, rowbase + reg)] = f2b(ov);
                    }
                } else {
                    // V pre-swizzled image: chunk = (bb*64 + s/64), 8192 elems each.
                    int bb = rowbase >> 12, s = rowbase & 4095;
                    int kc = s >> 6, g = (s >> 3) & 7;
                    ushort4 o;
                    o.x = f2b(v[0]); o.y = f2b(v[1]); o.z = f2b(v[2]); o.w = f2b(v[3]);
                    *(ushort4*)(((unsigned short*)Cv) + (size_t)2 * MTOT * 128 +
                                (((size_t)bb * 64 + kc) << 13) +
                                col * 64 + ((g ^ (col & 7)) << 3) + (s & 7)) = o;
                }
            }
        }
    }
}

// ---------------- Pass A: column sums L[k] = sum_q exp2(S[q,k]) — no P store ----------------
// Q fragments read DIRECTLY from the Q image (L2-resident); K staged once; NO barriers
// in the q loop (round-12-verified, big win).
__global__ __launch_bounds__(256) void colsum(
    const unsigned short* __restrict__ qh, const unsigned short* __restrict__ kh,
    float* __restrict__ psum_all)
{
    __shared__ unsigned short Ks[128 * 128];
    __shared__ float csum[2][128];
    const int b = blockIdx.z;
    const unsigned short* Q = qh + (size_t)b * S * 128;
    const unsigned short* Km = kh + (size_t)b * S * 128;
    const int bn = blockIdx.x * 128;
    const int q0 = blockIdx.y * (S / QSPLIT);
    const int tid = threadIdx.x;
    const int w = tid >> 6, l = tid & 63;
    const int wr = (w >> 1) * 64, wc = (w & 1) * 64;
    const int lm = l & 15, lq = l >> 4;

    // stage K tile once (image: linear DMA)
    #pragma unroll
    for (int i = 0; i < 8; ++i)
        gl_lds16(Km + (size_t)bn * 128 + (i * 256 + tid) * 8, Ks + (i * 256 + tid) * 8);
    __syncthreads();

    float jsum[4] = {0.f, 0.f, 0.f, 0.f};
    for (int qt = 0; qt < (S / QSPLIT) / 128; ++qt) {
        f32x4 zero = {0.f, 0.f, 0.f, 0.f};
        f32x4 acc[4][4];
        #pragma unroll
        for (int i = 0; i < 4; ++i)
            #pragma unroll
            for (int j = 0; j < 4; ++j) acc[i][j] = zero;

        #pragma unroll
        for (int ks = 0; ks < 4; ++ks) {
            bf16x8 a[4], bfr[4];
            #pragma unroll
            for (int i = 0; i < 4; ++i) {
                int m = wr + i * 16 + lm;      // m & 15 == lm
                a[i] = *(const bf16x8*)(Q + (size_t)(q0 + qt * 128 + m) * 128 +
                                        (((ks * 4 + lq) ^ lm) << 3));
            }
            #pragma unroll
            for (int j = 0; j < 4; ++j) {
                int n = wc + j * 16 + lm;
                int p = (ks * 4 + lq) ^ (n & 15);
                bfr[j] = *(const bf16x8*)(Ks + n * 128 + p * 8);
            }
            #pragma unroll
            for (int i = 0; i < 4; ++i)
                #pragma unroll
                for (int j = 0; j < 4; ++j)
                    acc[i][j] = __builtin_amdgcn_mfma_f32_16x16x32_bf16(a[i], bfr[j], acc[i][j], 0, 0, 0);
        }

        #pragma unroll
        for (int i = 0; i < 4; ++i)
            #pragma unroll
            for (int j = 0; j < 4; ++j)
                #pragma unroll
                for (int reg = 0; reg < 4; ++reg)
                    jsum[j] += exp2f(acc[i][j][reg]);
    }

    #pragma unroll
    for (int j = 0; j < 4; ++j) {
        jsum[j] += __shfl_xor(jsum[j], 16);
        jsum[j] += __shfl_xor(jsum[j], 32);
    }
    if (l < 16) {
        #pragma unroll
        for (int j = 0; j < 4; ++j)
            csum[w >> 1][wc + j * 16 + l] = jsum[j];
    }
    __syncthreads();
    if (tid < 128)
        psum_all[((size_t)(blockIdx.y * BATCH + b)) * S + bn + tid] = csum[0][tid] + csum[1][tid];
}

// ---------------- fold 1/L into V image (in place, bf16); k recovered from swizzled offset ----------------
__global__ __launch_bounds__(256) void vscale(
    unsigned short* __restrict__ Vimg_all, const float* __restrict__ psum_all)
{
    const int b = blockIdx.z;
    unsigned short* Vimg = Vimg_all + (size_t)b * CNUM * S;
    int i = (blockIdx.x * 256 + threadIdx.x) * 4;   // elem offset within batch image
    int kc = i >> 13;
    int off = i & 8191;
    int c = off >> 6;
    int p = (off >> 3) & 7;
    int g = p ^ (c & 7);
    int k = kc * 64 + g * 8 + (off & 7);
    float4 L = *(const float4*)(psum_all + (size_t)b * S + k);
    #pragma unroll
    for (int t = 1; t < QSPLIT; ++t) {
        float4 Lt = *(const float4*)(psum_all + ((size_t)(t * BATCH + b)) * S + k);
        L.x += Lt.x; L.y += Lt.y; L.z += Lt.z; L.w += Lt.w;
    }
    ushort4 v = *(ushort4*)(Vimg + i);
    v.x = f2b(b2f(v.x) / L.x);
    v.y = f2b(b2f(v.y) / L.y);
    v.z = f2b(b2f(v.z) / L.z);
    v.w = f2b(b2f(v.w) / L.w);
    *(ushort4*)(Vimg + i) = v;
}

// ---------------- fused attention: out_part = exp2(Q K^T) @ Vhat, k-split ----------------
// Round-11 structure (best measured 50.0 us): K single-buffer DMA (8 KB), V image chunk
// DMA every other tile (16 KB), issue->drain, 2 barriers/tile. DMA lands while waves wait
// at the barrier (no LDS port contention with compute — round-12 lesson). 32x32x16
// transposed QK^T; P via cvt_pk + permlane32_swap (no P LDS). Q pre-scaled. LDS 24 KB.
__global__ __launch_bounds__(256, 2) void fused_attnv(
    const unsigned short* __restrict__ qh, const unsigned short* __restrict__ kh,
    const unsigned short* __restrict__ Vimg_all, unsigned short* __restrict__ parts)
{
    __shared__ unsigned short Ks[32 * 128];      // 8 KB (image chunk, linear DMA)
    __shared__ unsigned short Vls[128 * 64];     // 16 KB image chunk (linear DMA)
    const int b = blockIdx.z;
    const unsigned short* Qm = qh + (size_t)b * S * 128;
    const unsigned short* Km = kh + (size_t)b * S * 128;
    const unsigned short* Vimg = Vimg_all + (((size_t)b * 64) << 13);
    unsigned short* Pout = parts + (size_t)blockIdx.x * ((size_t)MTOT * CNUM)
                                 + (size_t)b * S * CNUM;
    const int q0 = blockIdx.y * 128;
    const int kb0 = blockIdx.x * (S / KSPLIT);       // 512-k range
    const int kc0 = blockIdx.x * (S / KSPLIT / 64);  // first 64-k V chunk
    const int tid = threadIdx.x;
    const int w = tid >> 6, l = tid & 63;
    const int lc = l & 31, lh = l >> 5;              // col-lane, half
    const int row0 = q0 + w * 32;

    // Q B-fragments from the Q image (pre-scaled by SCLOG2E)
    bf16x8 aq[8];
    #pragma unroll
    for (int d = 0; d < 8; ++d)
        aq[d] = *(const bf16x8*)(Qm + (size_t)(row0 + lc) * 128 +
                                 (((d * 2 + lh) ^ (lc & 15)) << 3));

    f32x16 acco[4];
    #pragma unroll
    for (int cb = 0; cb < 4; ++cb)
        #pragma unroll
        for (int r = 0; r < 16; ++r) acco[cb][r] = 0.f;

    for (int kt = 0; kt < S / KSPLIT / 32; ++kt) {   // 16 tiles of 32 k
        const int kb = kb0 + kt * 32;
        if (kt) __syncthreads();                     // previous tile's Ks/Vls readers done
        // stage K tile [32][128] (image: linear DMA, 8 KB)
        #pragma unroll
        for (int i2 = 0; i2 < 2; ++i2)
            gl_lds16(Km + (size_t)kb * 128 + (i2 * 256 + tid) * 8,
                     Ks + (i2 * 256 + tid) * 8);
        // stage V 64-chunk every other tile (pre-swizzled image, linear DMA)
        if ((kt & 1) == 0) {
            const unsigned short* src = Vimg + ((size_t)(kc0 + (kt >> 1)) << 13) + tid * 8;
            #pragma unroll
            for (int i2 = 0; i2 < 4; ++i2)
                gl_lds16(src + i2 * 2048, &Vls[(i2 * 256 + tid) * 8]);
        }
        __syncthreads();

        // transposed QK^T: S^T; lane: q = lc, k = (reg&3)+8*(reg>>2)+4*lh
        f32x16 accT;
        #pragma unroll
        for (int r = 0; r < 16; ++r) accT[r] = 0.f;
        #pragma unroll
        for (int d = 0; d < 8; ++d) {
            int slot = d * 2 + lh;
            bf16x8 kf = *(const bf16x8*)(Ks + lc * 128 + ((slot ^ (lc & 15)) << 3));
            accT = __builtin_amdgcn_mfma_f32_32x32x16_bf16(kf, aq[d], accT, 0, 0, 0);
        }

        // P = exp2 (scale pre-folded into Q) -> bf16 pairs pk[t][p]
        unsigned int pk[4][2];
        #pragma unroll
        for (int t = 0; t < 4; ++t)
            #pragma unroll
            for (int p = 0; p < 2; ++p) {
                float e0 = exp2f(accT[t * 4 + 2 * p]);
                float e1 = exp2f(accT[t * 4 + 2 * p + 1]);
                asm("v_cvt_pk_bf16_f32 %0, %1, %2" : "=v"(pk[t][p]) : "v"(e0), "v"(e1));
            }
        // permlane32_swap: (t0,t1) -> A-frag k 0..15; (t2,t3) -> k 16..31 (round-6-verified)
        #pragma unroll
        for (int p = 0; p < 2; ++p) {
            asm volatile("v_permlane32_swap_b32 %0, %1" : "+v"(pk[0][p]), "+v"(pk[1][p]));
            asm volatile("v_permlane32_swap_b32 %0, %1" : "+v"(pk[2][p]), "+v"(pk[3][p]));
        }
        u32x4 u0 = {pk[0][0], pk[0][1], pk[1][0], pk[1][1]};
        u32x4 u1 = {pk[2][0], pk[2][1], pk[3][0], pk[3][1]};
        bf16x8 ap0 = __builtin_bit_cast(bf16x8, u0);
        bf16x8 ap1 = __builtin_bit_cast(bf16x8, u1);

        // PV B-frags from image chunk: g = (kt&1)*4 + khalf*2 + lh
        const int g0 = (kt & 1) * 4 + lh;
        const int g1 = g0 + 2;
        __builtin_amdgcn_s_setprio(1);
        #pragma unroll
        for (int cb = 0; cb < 4; ++cb) {
            int c = cb * 32 + lc;
            bf16x8 v0 = *(const bf16x8*)(Vls + c * 64 + ((g0 ^ (c & 7)) << 3));
            bf16x8 v1 = *(const bf16x8*)(Vls + c * 64 + ((g1 ^ (c & 7)) << 3));
            acco[cb] = __builtin_amdgcn_mfma_f32_32x32x16_bf16(ap0, v0, acco[cb], 0, 0, 0);
            acco[cb] = __builtin_amdgcn_mfma_f32_32x32x16_bf16(ap1, v1, acco[cb], 0, 0, 0);
        }
        __builtin_amdgcn_s_setprio(0);
    }

    #pragma unroll
    for (int cb = 0; cb < 4; ++cb)
        #pragma unroll
        for (int r = 0; r < 16; ++r) {
            int q = (r & 3) + 8 * (r >> 2) + 4 * lh;
            Pout[(size_t)(row0 + q) * CNUM + cb * 32 + lc] = f2b(acco[cb][r]);
        }
}

extern "C" void kernel_launch(void* const* d_in, const int* in_sizes, int n_in,
                              void* d_out, int out_size, void* d_ws, size_t ws_size,
                              hipStream_t stream)
{
    (void)in_sizes; (void)n_in; (void)out_size; (void)ws_size;
    const float* x    = (const float*)d_in[0];
    const float* ln1w = (const float*)d_in[1];
    const float* ln1b = (const float*)d_in[2];
    const float* wq   = (const float*)d_in[3];
    const float* bq   = (const float*)d_in[4];
    const float* wk   = (const float*)d_in[5];
    const float* bk   = (const float*)d_in[6];
    const float* wv   = (const float*)d_in[7];
    const float* bv   = (const float*)d_in[8];
    const float* wo   = (const float*)d_in[9];
    const float* bo   = (const float*)d_in[10];
    const float* ln2w = (const float*)d_in[11];
    const float* ln2b = (const float*)d_in[12];
    const float* w1   = (const float*)d_in[13];
    const float* b1   = (const float*)d_in[14];
    const float* w2   = (const float*)d_in[15];
    const float* b2   = (const float*)d_in[16];
    float* out = (float*)d_out;

    float* ws = (float*)d_ws;
    const size_t NSC = (size_t)MTOT * CNUM;            // 2,097,152
    float* t      = ws;
    float* y      = t + NSC;
    float* psum   = y + NSC;                           // [QSPLIT][B][S]
    unsigned short* parts = (unsigned short*)(psum + (size_t)QSPLIT * BATCH * S); // [KSPLIT][B][S][C]
    unsigned short* xlh = parts + (size_t)KSPLIT * NSC;
    unsigned short* qh  = xlh + NSC;
    unsigned short* kh  = qh + NSC;                    // V image must follow kh (EPI7 contiguity)
    unsigned short* Vt  = kh + NSC;                    // pre-swizzled V image
    unsigned short* zh  = Vt + NSC;
    unsigned short* hh  = zh + NSC;                    // [M,256] bf16 image
    unsigned short* wqkvh = hh + (size_t)MTOT * 256;
    unsigned short* woh = wqkvh + 3 * 16384;
    unsigned short* w1h = woh + 16384;                 // [256][128]
    unsigned short* w2h = w1h + 32768;                 // [128][256]
    float* bqkv = (float*)(w2h + 32768);               // [384]

    ln1_transpose<<<dim3(S / 64, BATCH), 256, 0, stream>>>(x, ln1w, ln1b, xlh, t);
    convw<<<dim3(128, 7), 256, 0, stream>>>(wq, wk, wv, wo, w1, w2, bq, bk, bv,
                                            wqkvh, woh, w1h, w2h, bqkv);

    // QKV: one launch, z = {q(scaled image), k(image), v(chunk image)} — BM=32, 1536 blocks
    gemm_mfma<128, 7, 32><<<dim3(1, MTOT / 32, 3), 256, 0, stream>>>(
        xlh, wqkvh, bqkv, nullptr, qh, nullptr, nullptr, nullptr, 128);

    colsum<<<dim3(S / 128, QSPLIT, BATCH), 256, 0, stream>>>(qh, kh, psum);
    vscale<<<dim3(CNUM * S / 4 / 256, 1, BATCH), 256, 0, stream>>>(Vt, psum);
    fused_attnv<<<dim3(KSPLIT, S / 128, BATCH), 256, 0, stream>>>(qh, kh, Vt, parts);

    // y = sum(parts) @ wo + bo + t (A-stage fused reduction), fused LN2 -> zh(image) — 512 blocks
    gemm_mfma<128, 3, 32><<<dim3(1, MTOT / 32), 256, 0, stream>>>(
        parts, woh, bo, t, y, zh, ln2w, ln2b, 128);
    // hh = gelu(zh @ w1 + b1) -> bf16 image — 1024 blocks
    gemm_mfma<128, 6, 32><<<dim3(2, MTOT / 32), 256, 0, stream>>>(
        zh, w1h, b1, nullptr, hh, nullptr, nullptr, nullptr, 256);
    // out[b][c][s] = gelu(hh @ w2 + b2) + y (fused transpose) — 512 blocks, 2-phase B
    gemm_mfma<256, 8, 32><<<dim3(1, MTOT / 32), 256, 0, stream>>>(
        hh, w2h, b2, y, out, nullptr, nullptr, nullptr, 128);
}

// Round 14
// 204.903 us; speedup vs baseline: 1.0250x; 1.0250x over previous
//
#include <hip/hip_runtime.h>
#include <math.h>

#define S 4096
#define CNUM 128
#define BATCH 4
#define MTOT (BATCH * S)
#define SCLOG2E 0.36067376022224085f   // 0.25 * log2(e): folded into Q at QKV epilogue
#define EPSLN 1e-5f
#define KSPLIT 4                        // k-range split for fused attn partials
#define QSPLIT 8                        // q-range split for column-sum pass

// All bf16 matrices ([row][128] or [row][256]) are stored as "swizzle images":
// element (row, col) lives at row*RL + ((col>>3 ^ (row&15))<<3) + (col&7).
// This is exactly the LDS layout every consumer kernel reads, so staging is a
// LINEAR global_load_lds DMA and all LDS-read code is unchanged.

typedef __attribute__((ext_vector_type(8))) short bf16x8;
typedef __attribute__((ext_vector_type(4))) float f32x4;
typedef __attribute__((ext_vector_type(16))) float f32x16;
typedef __attribute__((ext_vector_type(4))) unsigned int u32x4;

__device__ __forceinline__ float gelu_exact(float x) {
    return 0.5f * x * (1.0f + erff(x * 0.7071067811865476f));
}

__device__ __forceinline__ unsigned short f2b(float f) {
    union { float f; unsigned int u; } v; v.f = f;
    unsigned int r = (v.u + 0x7FFFu + ((v.u >> 16) & 1u)) >> 16;
    return (unsigned short)r;
}
__device__ __forceinline__ float b2f(unsigned short u) {
    return __uint_as_float((unsigned)u << 16);
}
// swizzled column offset within a row of an image matrix
__device__ __forceinline__ int swz(int col, int row) {
    return ((((col >> 3) ^ (row & 15)) << 3) | (col & 7));
}

// async 16B global->LDS (direct DMA, no VGPR round trip)
__device__ __forceinline__ void gl_lds16(const void* g, void* l) {
    __builtin_amdgcn_global_load_lds(
        (__attribute__((address_space(1))) void*)g,
        (__attribute__((address_space(3))) void*)l, 16, 0, 0);
}

// ---------------- transpose [B,C,S] -> [B,S,C]: t fp32 (residual), xlh bf16 image ----------------
__global__ __launch_bounds__(256) void ln1_transpose(
    const float* __restrict__ x, const float* __restrict__ w, const float* __restrict__ bb,
    unsigned short* __restrict__ xlh, float* __restrict__ t)
{
    __shared__ float tile[128][65];
    __shared__ float mu[64], rs[64];
    const int b = blockIdx.y;
    const int s0 = blockIdx.x * 64;
    const float* xb = x + (size_t)b * CNUM * S;
    for (int i = threadIdx.x; i < 128 * 64; i += 256) {
        int c = i >> 6, sl = i & 63;
        tile[c][sl] = xb[(size_t)c * S + s0 + sl];
    }
    __syncthreads();
    if (threadIdx.x < 64) {
        float sum = 0.f, sq = 0.f;
        for (int c = 0; c < 128; ++c) {
            float v = tile[c][threadIdx.x];
            sum += v; sq += v * v;
        }
        float m = sum * (1.f / 128.f);
        float var = sq * (1.f / 128.f) - m * m;
        mu[threadIdx.x] = m;
        rs[threadIdx.x] = rsqrtf(var + EPSLN);
    }
    __syncthreads();
    for (int i = threadIdx.x; i < 128 * 64; i += 256) {
        int c = i & 127, sl = i >> 7;
        float v = tile[c][sl];
        size_t row = (size_t)b * S + s0 + sl;
        t[row * CNUM + c] = v;
        xlh[row * CNUM + swz(c, sl)] = f2b((v - mu[sl]) * rs[sl] * w[c] + bb[c]);
    }
}

// ---------------- weight convert+transpose fp32[K,N] -> bf16 image [N][K]; biases packed ----------------
__global__ __launch_bounds__(256) void convw(
    const float* __restrict__ wq, const float* __restrict__ wk, const float* __restrict__ wv,
    const float* __restrict__ wo, const float* __restrict__ w1, const float* __restrict__ w2,
    const float* __restrict__ bq, const float* __restrict__ bk, const float* __restrict__ bv,
    unsigned short* __restrict__ wqkvh, unsigned short* __restrict__ woh,
    unsigned short* __restrict__ w1h, unsigned short* __restrict__ w2h,
    float* __restrict__ bqkv)
{
    int a = blockIdx.y;
    int idx = blockIdx.x * 256 + threadIdx.x;
    if (a == 6) {
        if (idx < 128) bqkv[idx] = bq[idx];
        else if (idx < 256) bqkv[idx] = bk[idx - 128];
        else if (idx < 384) bqkv[idx] = bv[idx - 256];
        return;
    }
    const float* src; unsigned short* dst; int Nsh, Ksz;
    switch (a) {
        case 0: src = wq; dst = wqkvh;          Nsh = 7; Ksz = 128; break;
        case 1: src = wk; dst = wqkvh + 16384;  Nsh = 7; Ksz = 128; break;
        case 2: src = wv; dst = wqkvh + 32768;  Nsh = 7; Ksz = 128; break;
        case 3: src = wo; dst = woh;            Nsh = 7; Ksz = 128; break;
        case 4: src = w1; dst = w1h;            Nsh = 8; Ksz = 128; break;
        default: src = w2; dst = w2h;           Nsh = 7; Ksz = 256; break;
    }
    int total = Ksz << Nsh;
    if (idx >= total) return;
    int k = idx >> Nsh, n = idx & ((1 << Nsh) - 1);
    dst[n * Ksz + swz(k, n)] = f2b(src[idx]);
}

// ---------------- MFMA GEMM: C = A[M,KT](image) @ Bt[N,KT]^T(image) + bias ----------------
// BM = M-tile (32: 4 waves x 32x32 each — 2x grid/occupancy vs 64).
// KT=256 stages B in two 128-k phases (Bs 32KB not 64KB) — k-ascending, bitwise-identical.
// EPI: 3 = A is KSPLIT part-slices (LINEAR) summed during staging; fp32 +res -> y AND LN2 -> zh image
//      6 = gelu -> bf16 image
//      7 = QKV (z=0: Q image scaled by SCLOG2E; z=1: K image; z=2: V chunk image)
//      8 = gelu + res -> fp32 out[b][col][s]
template<int KT, int EPI, int BM>
__global__ __launch_bounds__(256) void gemm_mfma(
    const unsigned short* __restrict__ A, const unsigned short* __restrict__ Bt,
    const float* __restrict__ bias, const float* __restrict__ res,
    void* __restrict__ Cv, void* __restrict__ Cv2,
    const float* __restrict__ wln, const float* __restrict__ bln, int N)
{
    constexpr int CH = KT / 8;
    constexpr int CSH = (KT == 128) ? 4 : 5;
    constexpr int BKT = (KT == 256) ? 128 : KT;    // B-stage K-phase width
    constexpr int NPH = KT / BKT;
    constexpr int NJ = (BM == 64) ? 4 : 2;         // N-frags per wave
    constexpr int NG = 128 / (NJ * 16);            // column groups (EPI3 LN)
    __shared__ unsigned short As[BM * KT];
    __shared__ unsigned short Bs[128 * BKT];
    __shared__ float2 lnred[(EPI == 3) ? NG * BM : 1];
    const int bm = blockIdx.y * BM;
    const int bn = blockIdx.x * 128;
    const int z = blockIdx.z;
    const unsigned short* Btz = (EPI == 7) ? Bt + z * 16384 : Bt;
    const float* biasz = (EPI == 7) ? bias + z * 128 : bias;
    const int tid = threadIdx.x;
    const int w = tid >> 6, l = tid & 63;
    const int rw = (BM == 64) ? (w & 1) * 32 : 0;
    const int cw = (BM == 64) ? (w >> 1) * 64 : w * 32;
    const int lm = l & 15, lq = l >> 4;

    f32x4 zero = {0.f, 0.f, 0.f, 0.f};
    f32x4 acc[2][NJ];
    #pragma unroll
    for (int i = 0; i < 2; ++i)
        #pragma unroll
        for (int j = 0; j < NJ; ++j) acc[i][j] = zero;

    #pragma unroll
    for (int ph = 0; ph < NPH; ++ph) {
        if (ph == 0) {
            if (EPI == 3) {
                // A-stage fused with the KSPLIT-partial reduction (parts is LINEAR layout)
                #pragma unroll
                for (int i = 0; i < (BM * CH) / 256; ++i) {
                    int cid = i * 256 + tid;
                    int r = cid >> CSH, c = cid & (CH - 1);
                    int p = (c & ~15) | ((c ^ r) & 15);
                    float s8[8];
                    #pragma unroll
                    for (int j = 0; j < 8; ++j) s8[j] = 0.f;
                    #pragma unroll
                    for (int pp = 0; pp < KSPLIT; ++pp) {
                        const unsigned short* src = A + (size_t)pp * ((size_t)MTOT * CNUM)
                                                      + (size_t)(bm + r) * KT + c * 8;
                        ushort4 u0 = *(const ushort4*)(src);
                        ushort4 u1 = *(const ushort4*)(src + 4);
                        s8[0] += b2f(u0.x); s8[1] += b2f(u0.y); s8[2] += b2f(u0.z); s8[3] += b2f(u0.w);
                        s8[4] += b2f(u1.x); s8[5] += b2f(u1.y); s8[6] += b2f(u1.z); s8[7] += b2f(u1.w);
                    }
                    ushort4 o0, o1;
                    o0.x = f2b(s8[0]); o0.y = f2b(s8[1]); o0.z = f2b(s8[2]); o0.w = f2b(s8[3]);
                    o1.x = f2b(s8[4]); o1.y = f2b(s8[5]); o1.z = f2b(s8[6]); o1.w = f2b(s8[7]);
                    *(ushort4*)(As + r * KT + p * 8) = o0;
                    *(ushort4*)(As + r * KT + p * 8 + 4) = o1;
                }
            } else {
                #pragma unroll
                for (int i = 0; i < (BM * CH) / 256; ++i)
                    gl_lds16(A + (size_t)bm * KT + (i * 256 + tid) * 8,
                             As + (i * 256 + tid) * 8);
            }
        } else {
            __syncthreads();   // previous phase's Bs readers done
        }
        // stage B phase ph: rows' [ph*BKT, +BKT) halves (contiguous 16B granules per row)
        #pragma unroll
        for (int i = 0; i < (128 * BKT / 8) / 256; ++i) {
            int cid = i * 256 + tid;
            int n = cid >> (CSH - (NPH - 1)), gg = cid & (BKT / 8 - 1);
            gl_lds16(Btz + (size_t)(bn + n) * KT + ph * BKT + gg * 8,
                     Bs + cid * 8);
        }
        __syncthreads();

        #pragma unroll
        for (int ks = 0; ks < BKT / 32; ++ks) {
            int c_loc = ks * 4 + lq;               // slot within phase (0..15)
            int c_glob = ph * 16 + c_loc;          // slot within full K row
            bf16x8 a[2], bfr[NJ];
            #pragma unroll
            for (int i = 0; i < 2; ++i) {
                int m = rw + i * 16 + lm;
                int p = (c_glob & ~15) | ((c_glob ^ m) & 15);
                a[i] = *(const bf16x8*)(As + m * KT + p * 8);
            }
            #pragma unroll
            for (int j = 0; j < NJ; ++j) {
                int n = cw + j * 16 + lm;
                int p = (c_loc ^ n) & 15;
                bfr[j] = *(const bf16x8*)(Bs + n * BKT + p * 8);
            }
            #pragma unroll
            for (int i = 0; i < 2; ++i)
                #pragma unroll
                for (int j = 0; j < NJ; ++j)
                    acc[i][j] = __builtin_amdgcn_mfma_f32_16x16x32_bf16(a[i], bfr[j], acc[i][j], 0, 0, 0);
        }
    }

    if (EPI == 3) {
        // y = acc + bias + res; then fused LN over the 128-col rows of this BM-row block.
        float vv[2][NJ][4];
        #pragma unroll
        for (int i = 0; i < 2; ++i) {
            int rowbase = bm + rw + i * 16 + lq * 4;
            #pragma unroll
            for (int j = 0; j < NJ; ++j) {
                int col = bn + cw + j * 16 + lm;
                #pragma unroll
                for (int reg = 0; reg < 4; ++reg)
                    vv[i][j][reg] = acc[i][j][reg] + biasz[col] +
                                    res[(size_t)(rowbase + reg) * N + col];
            }
        }
        #pragma unroll
        for (int i = 0; i < 2; ++i)
            #pragma unroll
            for (int reg = 0; reg < 4; ++reg) {
                float s = 0.f, q = 0.f;
                #pragma unroll
                for (int j = 0; j < NJ; ++j) {
                    float xv = vv[i][j][reg];
                    s += xv; q += xv * xv;
                }
                #pragma unroll
                for (int off = 1; off < 16; off <<= 1) {
                    s += __shfl_xor(s, off);
                    q += __shfl_xor(q, off);
                }
                if (lm == 0) {
                    float2 sq2; sq2.x = s; sq2.y = q;
                    lnred[(cw / (NJ * 16)) * BM + rw + i * 16 + lq * 4 + reg] = sq2;
                }
            }
        __syncthreads();
        #pragma unroll
        for (int i = 0; i < 2; ++i) {
            #pragma unroll
            for (int reg = 0; reg < 4; ++reg) {
                int lrow = rw + i * 16 + lq * 4 + reg;
                int row = bm + lrow;
                float sx = 0.f, sq = 0.f;
                #pragma unroll
                for (int g = 0; g < NG; ++g) {
                    float2 h = lnred[g * BM + lrow];
                    sx += h.x; sq += h.y;
                }
                float mean = sx * (1.f / 128.f);
                float var  = sq * (1.f / 128.f) - mean * mean;
                float rs = rsqrtf(var + EPSLN);
                #pragma unroll
                for (int j = 0; j < NJ; ++j) {
                    int col = bn + cw + j * 16 + lm;
                    float xv = vv[i][j][reg];
                    ((float*)Cv)[(size_t)row * N + col] = xv;
                    ((unsigned short*)Cv2)[(size_t)row * N + swz(col, lrow)] =
                        f2b((xv - mean) * rs * wln[col] + bln[col]);
                }
            }
        }
        return;
    }

    #pragma unroll
    for (int i = 0; i < 2; ++i) {
        int rowbase = bm + rw + i * 16 + lq * 4;
        #pragma unroll
        for (int j = 0; j < NJ; ++j) {
            int col = bn + cw + j * 16 + lm;
            float v[4];
            #pragma unroll
            for (int reg = 0; reg < 4; ++reg) v[reg] = acc[i][j][reg] + biasz[col];
            if (EPI == 6) {
                #pragma unroll
                for (int reg = 0; reg < 4; ++reg)
                    ((unsigned short*)Cv)[(size_t)(rowbase + reg) * N + swz(col, rowbase + reg)] =
                        f2b(gelu_exact(v[reg]));
            } else if (EPI == 8) {
                int bb = rowbase >> 12, s = rowbase & 4095;
                float4 o;
                o.x = gelu_exact(v[0]) + res[(size_t)(rowbase + 0) * N + col];
                o.y = gelu_exact(v[1]) + res[(size_t)(rowbase + 1) * N + col];
                o.z = gelu_exact(v[2]) + res[(size_t)(rowbase + 2) * N + col];
                o.w = gelu_exact(v[3]) + res[(size_t)(rowbase + 3) * N + col];
                *(float4*)(((float*)Cv) + ((size_t)(bb * 128 + col)) * 4096 + s) = o;
            } else if (EPI == 7) {
                if (z < 2) {
                    unsigned short* dst = ((unsigned short*)Cv) + (size_t)z * MTOT * 128;
                    #pragma unroll
                    for (int reg = 0; reg < 4; ++reg) {
                        float ov = (z == 0) ? v[reg] * SCLOG2E : v[reg];  // fold softmax scale into Q
                        dst[(size_t)(rowbase + reg) * 128 + swz(col, rowbase + reg)] = f2b(ov);
                    }
                } else {
                    // V pre-swizzled image: chunk = (bb*64 + s/64), 8192 elems each.
                    int bb = rowbase >> 12, s = rowbase & 4095;
                    int kc = s >> 6, g = (s >> 3) & 7;
                    ushort4 o;
                    o.x = f2b(v[0]); o.y = f2b(v[1]); o.z = f2b(v[2]); o.w = f2b(v[3]);
                    *(ushort4*)(((unsigned short*)Cv) + (size_t)2 * MTOT * 128 +
                                (((size_t)bb * 64 + kc) << 13) +
                                col * 64 + ((g ^ (col & 7)) << 3) + (s & 7)) = o;
                }
            }
        }
    }
}

// ---------------- Pass A: column sums L[k] = sum_q exp2(S[q,k]) — no P store ----------------
// Q fragments read DIRECTLY from the Q image (L2-resident); K staged once; NO barriers
// in the q loop (round-12-verified, big win).
__global__ __launch_bounds__(256) void colsum(
    const unsigned short* __restrict__ qh, const unsigned short* __restrict__ kh,
    float* __restrict__ psum_all)
{
    __shared__ unsigned short Ks[128 * 128];
    __shared__ float csum[2][128];
    const int b = blockIdx.z;
    const unsigned short* Q = qh + (size_t)b * S * 128;
    const unsigned short* Km = kh + (size_t)b * S * 128;
    const int bn = blockIdx.x * 128;
    const int q0 = blockIdx.y * (S / QSPLIT);
    const int tid = threadIdx.x;
    const int w = tid >> 6, l = tid & 63;
    const int wr = (w >> 1) * 64, wc = (w & 1) * 64;
    const int lm = l & 15, lq = l >> 4;

    // stage K tile once (image: linear DMA)
    #pragma unroll
    for (int i = 0; i < 8; ++i)
        gl_lds16(Km + (size_t)bn * 128 + (i * 256 + tid) * 8, Ks + (i * 256 + tid) * 8);
    __syncthreads();

    float jsum[4] = {0.f, 0.f, 0.f, 0.f};
    for (int qt = 0; qt < (S / QSPLIT) / 128; ++qt) {
        f32x4 zero = {0.f, 0.f, 0.f, 0.f};
        f32x4 acc[4][4];
        #pragma unroll
        for (int i = 0; i < 4; ++i)
            #pragma unroll
            for (int j = 0; j < 4; ++j) acc[i][j] = zero;

        #pragma unroll
        for (int ks = 0; ks < 4; ++ks) {
            bf16x8 a[4], bfr[4];
            #pragma unroll
            for (int i = 0; i < 4; ++i) {
                int m = wr + i * 16 + lm;      // m & 15 == lm
                a[i] = *(const bf16x8*)(Q + (size_t)(q0 + qt * 128 + m) * 128 +
                                        (((ks * 4 + lq) ^ lm) << 3));
            }
            #pragma unroll
            for (int j = 0; j < 4; ++j) {
                int n = wc + j * 16 + lm;
                int p = (ks * 4 + lq) ^ (n & 15);
                bfr[j] = *(const bf16x8*)(Ks + n * 128 + p * 8);
            }
            #pragma unroll
            for (int i = 0; i < 4; ++i)
                #pragma unroll
                for (int j = 0; j < 4; ++j)
                    acc[i][j] = __builtin_amdgcn_mfma_f32_16x16x32_bf16(a[i], bfr[j], acc[i][j], 0, 0, 0);
        }

        #pragma unroll
        for (int i = 0; i < 4; ++i)
            #pragma unroll
            for (int j = 0; j < 4; ++j)
                #pragma unroll
                for (int reg = 0; reg < 4; ++reg)
                    jsum[j] += exp2f(acc[i][j][reg]);
    }

    #pragma unroll
    for (int j = 0; j < 4; ++j) {
        jsum[j] += __shfl_xor(jsum[j], 16);
        jsum[j] += __shfl_xor(jsum[j], 32);
    }
    if (l < 16) {
        #pragma unroll
        for (int j = 0; j < 4; ++j)
            csum[w >> 1][wc + j * 16 + l] = jsum[j];
    }
    __syncthreads();
    if (tid < 128)
        psum_all[((size_t)(blockIdx.y * BATCH + b)) * S + bn + tid] = csum[0][tid] + csum[1][tid];
}

// ---------------- fold 1/L into V image (in place, bf16); k recovered from swizzled offset ----------------
__global__ __launch_bounds__(256) void vscale(
    unsigned short* __restrict__ Vimg_all, const float* __restrict__ psum_all)
{
    const int b = blockIdx.z;
    unsigned short* Vimg = Vimg_all + (size_t)b * CNUM * S;
    int i = (blockIdx.x * 256 + threadIdx.x) * 4;   // elem offset within batch image
    int kc = i >> 13;
    int off = i & 8191;
    int c = off >> 6;
    int p = (off >> 3) & 7;
    int g = p ^ (c & 7);
    int k = kc * 64 + g * 8 + (off & 7);
    float4 L = *(const float4*)(psum_all + (size_t)b * S + k);
    #pragma unroll
    for (int t = 1; t < QSPLIT; ++t) {
        float4 Lt = *(const float4*)(psum_all + ((size_t)(t * BATCH + b)) * S + k);
        L.x += Lt.x; L.y += Lt.y; L.z += Lt.z; L.w += Lt.w;
    }
    ushort4 v = *(ushort4*)(Vimg + i);
    v.x = f2b(b2f(v.x) / L.x);
    v.y = f2b(b2f(v.y) / L.y);
    v.z = f2b(b2f(v.z) / L.z);
    v.w = f2b(b2f(v.w) / L.w);
    *(ushort4*)(Vimg + i) = v;
}

// ---------------- fused attention: out_part = exp2(Q K^T) @ Vhat, k-split ----------------
// Round-11/13 structure: K single-buffer DMA (8 KB), V image chunk DMA every other tile
// (16 KB), issue->drain, 2 barriers/tile (all pipelining variants measured within noise).
// KSPLIT=4: 32 tiles/block, halves parts traffic. setprio removed (lockstep waves — m190
// regime, null-to-negative). 32x32x16 transposed QK^T; P via cvt_pk + permlane32_swap
// (no P LDS). Q pre-scaled by SCLOG2E. LDS 24 KB.
__global__ __launch_bounds__(256, 2) void fused_attnv(
    const unsigned short* __restrict__ qh, const unsigned short* __restrict__ kh,
    const unsigned short* __restrict__ Vimg_all, unsigned short* __restrict__ parts)
{
    __shared__ unsigned short Ks[32 * 128];      // 8 KB (image chunk, linear DMA)
    __shared__ unsigned short Vls[128 * 64];     // 16 KB image chunk (linear DMA)
    const int b = blockIdx.z;
    const unsigned short* Qm = qh + (size_t)b * S * 128;
    const unsigned short* Km = kh + (size_t)b * S * 128;
    const unsigned short* Vimg = Vimg_all + (((size_t)b * 64) << 13);
    unsigned short* Pout = parts + (size_t)blockIdx.x * ((size_t)MTOT * CNUM)
                                 + (size_t)b * S * CNUM;
    const int q0 = blockIdx.y * 128;
    const int kb0 = blockIdx.x * (S / KSPLIT);       // 1024-k range
    const int kc0 = blockIdx.x * (S / KSPLIT / 64);  // first 64-k V chunk
    const int tid = threadIdx.x;
    const int w = tid >> 6, l = tid & 63;
    const int lc = l & 31, lh = l >> 5;              // col-lane, half
    const int row0 = q0 + w * 32;

    // Q B-fragments from the Q image (pre-scaled by SCLOG2E)
    bf16x8 aq[8];
    #pragma unroll
    for (int d = 0; d < 8; ++d)
        aq[d] = *(const bf16x8*)(Qm + (size_t)(row0 + lc) * 128 +
                                 (((d * 2 + lh) ^ (lc & 15)) << 3));

    f32x16 acco[4];
    #pragma unroll
    for (int cb = 0; cb < 4; ++cb)
        #pragma unroll
        for (int r = 0; r < 16; ++r) acco[cb][r] = 0.f;

    for (int kt = 0; kt < S / KSPLIT / 32; ++kt) {   // 32 tiles of 32 k
        const int kb = kb0 + kt * 32;
        if (kt) __syncthreads();                     // previous tile's Ks/Vls readers done
        // stage K tile [32][128] (image: linear DMA, 8 KB)
        #pragma unroll
        for (int i2 = 0; i2 < 2; ++i2)
            gl_lds16(Km + (size_t)kb * 128 + (i2 * 256 + tid) * 8,
                     Ks + (i2 * 256 + tid) * 8);
        // stage V 64-chunk every other tile (pre-swizzled image, linear DMA)
        if ((kt & 1) == 0) {
            const unsigned short* src = Vimg + ((size_t)(kc0 + (kt >> 1)) << 13) + tid * 8;
            #pragma unroll
            for (int i2 = 0; i2 < 4; ++i2)
                gl_lds16(src + i2 * 2048, &Vls[(i2 * 256 + tid) * 8]);
        }
        __syncthreads();

        // transposed QK^T: S^T; lane: q = lc, k = (reg&3)+8*(reg>>2)+4*lh
        f32x16 accT;
        #pragma unroll
        for (int r = 0; r < 16; ++r) accT[r] = 0.f;
        #pragma unroll
        for (int d = 0; d < 8; ++d) {
            int slot = d * 2 + lh;
            bf16x8 kf = *(const bf16x8*)(Ks + lc * 128 + ((slot ^ (lc & 15)) << 3));
            accT = __builtin_amdgcn_mfma_f32_32x32x16_bf16(kf, aq[d], accT, 0, 0, 0);
        }

        // P = exp2 (scale pre-folded into Q) -> bf16 pairs pk[t][p]
        unsigned int pk[4][2];
        #pragma unroll
        for (int t = 0; t < 4; ++t)
            #pragma unroll
            for (int p = 0; p < 2; ++p) {
                float e0 = exp2f(accT[t * 4 + 2 * p]);
                float e1 = exp2f(accT[t * 4 + 2 * p + 1]);
                asm("v_cvt_pk_bf16_f32 %0, %1, %2" : "=v"(pk[t][p]) : "v"(e0), "v"(e1));
            }
        // permlane32_swap: (t0,t1) -> A-frag k 0..15; (t2,t3) -> k 16..31 (round-6-verified)
        #pragma unroll
        for (int p = 0; p < 2; ++p) {
            asm volatile("v_permlane32_swap_b32 %0, %1" : "+v"(pk[0][p]), "+v"(pk[1][p]));
            asm volatile("v_permlane32_swap_b32 %0, %1" : "+v"(pk[2][p]), "+v"(pk[3][p]));
        }
        u32x4 u0 = {pk[0][0], pk[0][1], pk[1][0], pk[1][1]};
        u32x4 u1 = {pk[2][0], pk[2][1], pk[3][0], pk[3][1]};
        bf16x8 ap0 = __builtin_bit_cast(bf16x8, u0);
        bf16x8 ap1 = __builtin_bit_cast(bf16x8, u1);

        // PV B-frags from image chunk: g = (kt&1)*4 + khalf*2 + lh
        const int g0 = (kt & 1) * 4 + lh;
        const int g1 = g0 + 2;
        #pragma unroll
        for (int cb = 0; cb < 4; ++cb) {
            int c = cb * 32 + lc;
            bf16x8 v0 = *(const bf16x8*)(Vls + c * 64 + ((g0 ^ (c & 7)) << 3));
            bf16x8 v1 = *(const bf16x8*)(Vls + c * 64 + ((g1 ^ (c & 7)) << 3));
            acco[cb] = __builtin_amdgcn_mfma_f32_32x32x16_bf16(ap0, v0, acco[cb], 0, 0, 0);
            acco[cb] = __builtin_amdgcn_mfma_f32_32x32x16_bf16(ap1, v1, acco[cb], 0, 0, 0);
        }
    }

    #pragma unroll
    for (int cb = 0; cb < 4; ++cb)
        #pragma unroll
        for (int r = 0; r < 16; ++r) {
            int q = (r & 3) + 8 * (r >> 2) + 4 * lh;
            Pout[(size_t)(row0 + q) * CNUM + cb * 32 + lc] = f2b(acco[cb][r]);
        }
}

extern "C" void kernel_launch(void* const* d_in, const int* in_sizes, int n_in,
                              void* d_out, int out_size, void* d_ws, size_t ws_size,
                              hipStream_t stream)
{
    (void)in_sizes; (void)n_in; (void)out_size; (void)ws_size;
    const float* x    = (const float*)d_in[0];
    const float* ln1w = (const float*)d_in[1];
    const float* ln1b = (const float*)d_in[2];
    const float* wq   = (const float*)d_in[3];
    const float* bq   = (const float*)d_in[4];
    const float* wk   = (const float*)d_in[5];
    const float* bk   = (const float*)d_in[6];
    const float* wv   = (const float*)d_in[7];
    const float* bv   = (const float*)d_in[8];
    const float* wo   = (const float*)d_in[9];
    const float* bo   = (const float*)d_in[10];
    const float* ln2w = (const float*)d_in[11];
    const float* ln2b = (const float*)d_in[12];
    const float* w1   = (const float*)d_in[13];
    const float* b1   = (const float*)d_in[14];
    const float* w2   = (const float*)d_in[15];
    const float* b2   = (const float*)d_in[16];
    float* out = (float*)d_out;

    float* ws = (float*)d_ws;
    const size_t NSC = (size_t)MTOT * CNUM;            // 2,097,152
    float* t      = ws;
    float* y      = t + NSC;
    float* psum   = y + NSC;                           // [QSPLIT][B][S]
    unsigned short* parts = (unsigned short*)(psum + (size_t)QSPLIT * BATCH * S); // [KSPLIT][B][S][C]
    unsigned short* xlh = parts + (size_t)KSPLIT * NSC;
    unsigned short* qh  = xlh + NSC;
    unsigned short* kh  = qh + NSC;                    // V image must follow kh (EPI7 contiguity)
    unsigned short* Vt  = kh + NSC;                    // pre-swizzled V image
    unsigned short* zh  = Vt + NSC;
    unsigned short* hh  = zh + NSC;                    // [M,256] bf16 image
    unsigned short* wqkvh = hh + (size_t)MTOT * 256;
    unsigned short* woh = wqkvh + 3 * 16384;
    unsigned short* w1h = woh + 16384;                 // [256][128]
    unsigned short* w2h = w1h + 32768;                 // [128][256]
    float* bqkv = (float*)(w2h + 32768);               // [384]

    ln1_transpose<<<dim3(S / 64, BATCH), 256, 0, stream>>>(x, ln1w, ln1b, xlh, t);
    convw<<<dim3(128, 7), 256, 0, stream>>>(wq, wk, wv, wo, w1, w2, bq, bk, bv,
                                            wqkvh, woh, w1h, w2h, bqkv);

    // QKV: one launch, z = {q(scaled image), k(image), v(chunk image)} — BM=32, 1536 blocks
    gemm_mfma<128, 7, 32><<<dim3(1, MTOT / 32, 3), 256, 0, stream>>>(
        xlh, wqkvh, bqkv, nullptr, qh, nullptr, nullptr, nullptr, 128);

    colsum<<<dim3(S / 128, QSPLIT, BATCH), 256, 0, stream>>>(qh, kh, psum);
    vscale<<<dim3(CNUM * S / 4 / 256, 1, BATCH), 256, 0, stream>>>(Vt, psum);
    fused_attnv<<<dim3(KSPLIT, S / 128, BATCH), 256, 0, stream>>>(qh, kh, Vt, parts);

    // y = sum(parts) @ wo + bo + t (A-stage fused reduction), fused LN2 -> zh(image) — 512 blocks
    gemm_mfma<128, 3, 32><<<dim3(1, MTOT / 32), 256, 0, stream>>>(
        parts, woh, bo, t, y, zh, ln2w, ln2b, 128);
    // hh = gelu(zh @ w1 + b1) -> bf16 image — 1024 blocks
    gemm_mfma<128, 6, 32><<<dim3(2, MTOT / 32), 256, 0, stream>>>(
        zh, w1h, b1, nullptr, hh, nullptr, nullptr, nullptr, 256);
    // out[b][c][s] = gelu(hh @ w2 + b2) + y (fused transpose) — 512 blocks, 2-phase B
    gemm_mfma<256, 8, 32><<<dim3(1, MTOT / 32), 256, 0, stream>>>(
        hh, w2h, b2, y, out, nullptr, nullptr, nullptr, 128);
}

// Round 15
// 199.756 us; speedup vs baseline: 1.0514x; 1.0258x over previous
//
#include <hip/hip_runtime.h>
#include <math.h>

#define S 4096
#define CNUM 128
#define BATCH 4
#define MTOT (BATCH * S)
#define SCLOG2E 0.36067376022224085f   // 0.25 * log2(e): folded into Q at QKV epilogue
#define EPSLN 1e-5f
#define KSPLIT 4                        // k-range split for fused attn partials
#define QSPLIT 8                        // q-range split for column-sum pass

// All bf16 matrices ([row][128] or [row][256]) are stored as "swizzle images":
// element (row, col) lives at row*RL + ((col>>3 ^ (row&15))<<3) + (col&7).
// This is exactly the LDS layout every consumer kernel reads, so staging is a
// LINEAR global_load_lds DMA and all LDS-read code is unchanged.

typedef __attribute__((ext_vector_type(8))) short bf16x8;
typedef __attribute__((ext_vector_type(4))) float f32x4;
typedef __attribute__((ext_vector_type(16))) float f32x16;
typedef __attribute__((ext_vector_type(4))) unsigned int u32x4;

__device__ __forceinline__ float gelu_exact(float x) {
    return 0.5f * x * (1.0f + erff(x * 0.7071067811865476f));
}

__device__ __forceinline__ unsigned short f2b(float f) {
    union { float f; unsigned int u; } v; v.f = f;
    unsigned int r = (v.u + 0x7FFFu + ((v.u >> 16) & 1u)) >> 16;
    return (unsigned short)r;
}
__device__ __forceinline__ float b2f(unsigned short u) {
    return __uint_as_float((unsigned)u << 16);
}
// swizzled column offset within a row of an image matrix
__device__ __forceinline__ int swz(int col, int row) {
    return ((((col >> 3) ^ (row & 15)) << 3) | (col & 7));
}

// async 16B global->LDS (direct DMA, no VGPR round trip)
__device__ __forceinline__ void gl_lds16(const void* g, void* l) {
    __builtin_amdgcn_global_load_lds(
        (__attribute__((address_space(1))) void*)g,
        (__attribute__((address_space(3))) void*)l, 16, 0, 0);
}

// ---------------- transpose [B,C,S] -> [B,S,C]: t fp32 (residual), xlh bf16 image ----------------
__global__ __launch_bounds__(256) void ln1_transpose(
    const float* __restrict__ x, const float* __restrict__ w, const float* __restrict__ bb,
    unsigned short* __restrict__ xlh, float* __restrict__ t)
{
    __shared__ float tile[128][65];
    __shared__ float mu[64], rs[64];
    const int b = blockIdx.y;
    const int s0 = blockIdx.x * 64;
    const float* xb = x + (size_t)b * CNUM * S;
    for (int i = threadIdx.x; i < 128 * 64; i += 256) {
        int c = i >> 6, sl = i & 63;
        tile[c][sl] = xb[(size_t)c * S + s0 + sl];
    }
    __syncthreads();
    if (threadIdx.x < 64) {
        float sum = 0.f, sq = 0.f;
        for (int c = 0; c < 128; ++c) {
            float v = tile[c][threadIdx.x];
            sum += v; sq += v * v;
        }
        float m = sum * (1.f / 128.f);
        float var = sq * (1.f / 128.f) - m * m;
        mu[threadIdx.x] = m;
        rs[threadIdx.x] = rsqrtf(var + EPSLN);
    }
    __syncthreads();
    for (int i = threadIdx.x; i < 128 * 64; i += 256) {
        int c = i & 127, sl = i >> 7;
        float v = tile[c][sl];
        size_t row = (size_t)b * S + s0 + sl;
        t[row * CNUM + c] = v;
        xlh[row * CNUM + swz(c, sl)] = f2b((v - mu[sl]) * rs[sl] * w[c] + bb[c]);
    }
}

// ---------------- weight convert+transpose fp32[K,N] -> bf16 image [N][K]; biases packed ----------------
__global__ __launch_bounds__(256) void convw(
    const float* __restrict__ wq, const float* __restrict__ wk, const float* __restrict__ wv,
    const float* __restrict__ wo, const float* __restrict__ w1, const float* __restrict__ w2,
    const float* __restrict__ bq, const float* __restrict__ bk, const float* __restrict__ bv,
    unsigned short* __restrict__ wqkvh, unsigned short* __restrict__ woh,
    unsigned short* __restrict__ w1h, unsigned short* __restrict__ w2h,
    float* __restrict__ bqkv)
{
    int a = blockIdx.y;
    int idx = blockIdx.x * 256 + threadIdx.x;
    if (a == 6) {
        if (idx < 128) bqkv[idx] = bq[idx];
        else if (idx < 256) bqkv[idx] = bk[idx - 128];
        else if (idx < 384) bqkv[idx] = bv[idx - 256];
        return;
    }
    const float* src; unsigned short* dst; int Nsh, Ksz;
    switch (a) {
        case 0: src = wq; dst = wqkvh;          Nsh = 7; Ksz = 128; break;
        case 1: src = wk; dst = wqkvh + 16384;  Nsh = 7; Ksz = 128; break;
        case 2: src = wv; dst = wqkvh + 32768;  Nsh = 7; Ksz = 128; break;
        case 3: src = wo; dst = woh;            Nsh = 7; Ksz = 128; break;
        case 4: src = w1; dst = w1h;            Nsh = 8; Ksz = 128; break;
        default: src = w2; dst = w2h;           Nsh = 7; Ksz = 256; break;
    }
    int total = Ksz << Nsh;
    if (idx >= total) return;
    int k = idx >> Nsh, n = idx & ((1 << Nsh) - 1);
    dst[n * Ksz + swz(k, n)] = f2b(src[idx]);
}

// ---------------- MFMA GEMM (QKV only): C = A[M,128](image) @ Bt[128,128]^T(image) + bias ----------------
// EPI 7: z=0: Q image scaled by SCLOG2E; z=1: K image; z=2: V chunk image.
template<int KT, int EPI, int BM>
__global__ __launch_bounds__(256) void gemm_mfma(
    const unsigned short* __restrict__ A, const unsigned short* __restrict__ Bt,
    const float* __restrict__ bias, const float* __restrict__ res,
    void* __restrict__ Cv, void* __restrict__ Cv2,
    const float* __restrict__ wln, const float* __restrict__ bln, int N)
{
    constexpr int CH = KT / 8;
    constexpr int NJ = (BM == 64) ? 4 : 2;
    __shared__ unsigned short As[BM * KT];
    __shared__ unsigned short Bs[128 * KT];
    const int bm = blockIdx.y * BM;
    const int bn = blockIdx.x * 128;
    const int z = blockIdx.z;
    const unsigned short* Btz = (EPI == 7) ? Bt + z * 16384 : Bt;
    const float* biasz = (EPI == 7) ? bias + z * 128 : bias;
    const int tid = threadIdx.x;
    const int w = tid >> 6, l = tid & 63;
    const int rw = (BM == 64) ? (w & 1) * 32 : 0;
    const int cw = (BM == 64) ? (w >> 1) * 64 : w * 32;
    const int lm = l & 15, lq = l >> 4;

    #pragma unroll
    for (int i = 0; i < (BM * CH) / 256; ++i)
        gl_lds16(A + (size_t)bm * KT + (i * 256 + tid) * 8, As + (i * 256 + tid) * 8);
    #pragma unroll
    for (int i = 0; i < (128 * CH) / 256; ++i)
        gl_lds16(Btz + (size_t)bn * KT + (i * 256 + tid) * 8, Bs + (i * 256 + tid) * 8);
    __syncthreads();

    f32x4 zero = {0.f, 0.f, 0.f, 0.f};
    f32x4 acc[2][NJ];
    #pragma unroll
    for (int i = 0; i < 2; ++i)
        #pragma unroll
        for (int j = 0; j < NJ; ++j) acc[i][j] = zero;

    #pragma unroll
    for (int ks = 0; ks < KT / 32; ++ks) {
        int c_lin = ks * 4 + lq;
        bf16x8 a[2], bfr[NJ];
        #pragma unroll
        for (int i = 0; i < 2; ++i) {
            int m = rw + i * 16 + lm;
            int p = (c_lin & ~15) | ((c_lin ^ m) & 15);
            a[i] = *(const bf16x8*)(As + m * KT + p * 8);
        }
        #pragma unroll
        for (int j = 0; j < NJ; ++j) {
            int n = cw + j * 16 + lm;
            int p = (c_lin & ~15) | ((c_lin ^ n) & 15);
            bfr[j] = *(const bf16x8*)(Bs + n * KT + p * 8);
        }
        #pragma unroll
        for (int i = 0; i < 2; ++i)
            #pragma unroll
            for (int j = 0; j < NJ; ++j)
                acc[i][j] = __builtin_amdgcn_mfma_f32_16x16x32_bf16(a[i], bfr[j], acc[i][j], 0, 0, 0);
    }

    #pragma unroll
    for (int i = 0; i < 2; ++i) {
        int rowbase = bm + rw + i * 16 + lq * 4;
        #pragma unroll
        for (int j = 0; j < NJ; ++j) {
            int col = bn + cw + j * 16 + lm;
            float v[4];
            #pragma unroll
            for (int reg = 0; reg < 4; ++reg) v[reg] = acc[i][j][reg] + biasz[col];
            if (z < 2) {
                unsigned short* dst = ((unsigned short*)Cv) + (size_t)z * MTOT * 128;
                #pragma unroll
                for (int reg = 0; reg < 4; ++reg) {
                    float ov = (z == 0) ? v[reg] * SCLOG2E : v[reg];  // fold softmax scale into Q
                    dst[(size_t)(rowbase + reg) * 128 + swz(col, rowbase + reg)] = f2b(ov);
                }
            } else {
                // V pre-swizzled image: chunk = (bb*64 + s/64), 8192 elems each.
                int bb = rowbase >> 12, s = rowbase & 4095;
                int kc = s >> 6, g = (s >> 3) & 7;
                ushort4 o;
                o.x = f2b(v[0]); o.y = f2b(v[1]); o.z = f2b(v[2]); o.w = f2b(v[3]);
                *(ushort4*)(((unsigned short*)Cv) + (size_t)2 * MTOT * 128 +
                            (((size_t)bb * 64 + kc) << 13) +
                            col * 64 + ((g ^ (col & 7)) << 3) + (s & 7)) = o;
            }
        }
    }
}

// ---------------- Pass A: column sums L[k] = sum_q exp2(S[q,k]) — no P store ----------------
// Q fragments read DIRECTLY from the Q image (L2-resident); K staged once; NO barriers
// in the q loop (round-12-verified, big win).
__global__ __launch_bounds__(256) void colsum(
    const unsigned short* __restrict__ qh, const unsigned short* __restrict__ kh,
    float* __restrict__ psum_all)
{
    __shared__ unsigned short Ks[128 * 128];
    __shared__ float csum[2][128];
    const int b = blockIdx.z;
    const unsigned short* Q = qh + (size_t)b * S * 128;
    const unsigned short* Km = kh + (size_t)b * S * 128;
    const int bn = blockIdx.x * 128;
    const int q0 = blockIdx.y * (S / QSPLIT);
    const int tid = threadIdx.x;
    const int w = tid >> 6, l = tid & 63;
    const int wr = (w >> 1) * 64, wc = (w & 1) * 64;
    const int lm = l & 15, lq = l >> 4;

    // stage K tile once (image: linear DMA)
    #pragma unroll
    for (int i = 0; i < 8; ++i)
        gl_lds16(Km + (size_t)bn * 128 + (i * 256 + tid) * 8, Ks + (i * 256 + tid) * 8);
    __syncthreads();

    float jsum[4] = {0.f, 0.f, 0.f, 0.f};
    for (int qt = 0; qt < (S / QSPLIT) / 128; ++qt) {
        f32x4 zero = {0.f, 0.f, 0.f, 0.f};
        f32x4 acc[4][4];
        #pragma unroll
        for (int i = 0; i < 4; ++i)
            #pragma unroll
            for (int j = 0; j < 4; ++j) acc[i][j] = zero;

        #pragma unroll
        for (int ks = 0; ks < 4; ++ks) {
            bf16x8 a[4], bfr[4];
            #pragma unroll
            for (int i = 0; i < 4; ++i) {
                int m = wr + i * 16 + lm;      // m & 15 == lm
                a[i] = *(const bf16x8*)(Q + (size_t)(q0 + qt * 128 + m) * 128 +
                                        (((ks * 4 + lq) ^ lm) << 3));
            }
            #pragma unroll
            for (int j = 0; j < 4; ++j) {
                int n = wc + j * 16 + lm;
                int p = (ks * 4 + lq) ^ (n & 15);
                bfr[j] = *(const bf16x8*)(Ks + n * 128 + p * 8);
            }
            #pragma unroll
            for (int i = 0; i < 4; ++i)
                #pragma unroll
                for (int j = 0; j < 4; ++j)
                    acc[i][j] = __builtin_amdgcn_mfma_f32_16x16x32_bf16(a[i], bfr[j], acc[i][j], 0, 0, 0);
        }

        #pragma unroll
        for (int i = 0; i < 4; ++i)
            #pragma unroll
            for (int j = 0; j < 4; ++j)
                #pragma unroll
                for (int reg = 0; reg < 4; ++reg)
                    jsum[j] += exp2f(acc[i][j][reg]);
    }

    #pragma unroll
    for (int j = 0; j < 4; ++j) {
        jsum[j] += __shfl_xor(jsum[j], 16);
        jsum[j] += __shfl_xor(jsum[j], 32);
    }
    if (l < 16) {
        #pragma unroll
        for (int j = 0; j < 4; ++j)
            csum[w >> 1][wc + j * 16 + l] = jsum[j];
    }
    __syncthreads();
    if (tid < 128)
        psum_all[((size_t)(blockIdx.y * BATCH + b)) * S + bn + tid] = csum[0][tid] + csum[1][tid];
}

// ---------------- fold 1/L into V image (in place, bf16); k recovered from swizzled offset ----------------
__global__ __launch_bounds__(256) void vscale(
    unsigned short* __restrict__ Vimg_all, const float* __restrict__ psum_all)
{
    const int b = blockIdx.z;
    unsigned short* Vimg = Vimg_all + (size_t)b * CNUM * S;
    int i = (blockIdx.x * 256 + threadIdx.x) * 4;   // elem offset within batch image
    int kc = i >> 13;
    int off = i & 8191;
    int c = off >> 6;
    int p = (off >> 3) & 7;
    int g = p ^ (c & 7);
    int k = kc * 64 + g * 8 + (off & 7);
    float4 L = *(const float4*)(psum_all + (size_t)b * S + k);
    #pragma unroll
    for (int t = 1; t < QSPLIT; ++t) {
        float4 Lt = *(const float4*)(psum_all + ((size_t)(t * BATCH + b)) * S + k);
        L.x += Lt.x; L.y += Lt.y; L.z += Lt.z; L.w += Lt.w;
    }
    ushort4 v = *(ushort4*)(Vimg + i);
    v.x = f2b(b2f(v.x) / L.x);
    v.y = f2b(b2f(v.y) / L.y);
    v.z = f2b(b2f(v.z) / L.z);
    v.w = f2b(b2f(v.w) / L.w);
    *(ushort4*)(Vimg + i) = v;
}

// ---------------- fused attention: out_part = exp2(Q K^T) @ Vhat, k-split ----------------
// Round-14 structure: K single-buffer DMA (8 KB), V image chunk DMA every other tile
// (16 KB), issue->drain, 2 barriers/tile. KSPLIT=4. 32x32x16 transposed QK^T; P via
// cvt_pk + permlane32_swap (no P LDS). Q pre-scaled by SCLOG2E. LDS 24 KB.
__global__ __launch_bounds__(256, 2) void fused_attnv(
    const unsigned short* __restrict__ qh, const unsigned short* __restrict__ kh,
    const unsigned short* __restrict__ Vimg_all, unsigned short* __restrict__ parts)
{
    __shared__ unsigned short Ks[32 * 128];      // 8 KB (image chunk, linear DMA)
    __shared__ unsigned short Vls[128 * 64];     // 16 KB image chunk (linear DMA)
    const int b = blockIdx.z;
    const unsigned short* Qm = qh + (size_t)b * S * 128;
    const unsigned short* Km = kh + (size_t)b * S * 128;
    const unsigned short* Vimg = Vimg_all + (((size_t)b * 64) << 13);
    unsigned short* Pout = parts + (size_t)blockIdx.x * ((size_t)MTOT * CNUM)
                                 + (size_t)b * S * CNUM;
    const int q0 = blockIdx.y * 128;
    const int kb0 = blockIdx.x * (S / KSPLIT);       // 1024-k range
    const int kc0 = blockIdx.x * (S / KSPLIT / 64);  // first 64-k V chunk
    const int tid = threadIdx.x;
    const int w = tid >> 6, l = tid & 63;
    const int lc = l & 31, lh = l >> 5;              // col-lane, half
    const int row0 = q0 + w * 32;

    // Q B-fragments from the Q image (pre-scaled by SCLOG2E)
    bf16x8 aq[8];
    #pragma unroll
    for (int d = 0; d < 8; ++d)
        aq[d] = *(const bf16x8*)(Qm + (size_t)(row0 + lc) * 128 +
                                 (((d * 2 + lh) ^ (lc & 15)) << 3));

    f32x16 acco[4];
    #pragma unroll
    for (int cb = 0; cb < 4; ++cb)
        #pragma unroll
        for (int r = 0; r < 16; ++r) acco[cb][r] = 0.f;

    for (int kt = 0; kt < S / KSPLIT / 32; ++kt) {   // 32 tiles of 32 k
        const int kb = kb0 + kt * 32;
        if (kt) __syncthreads();                     // previous tile's Ks/Vls readers done
        // stage K tile [32][128] (image: linear DMA, 8 KB)
        #pragma unroll
        for (int i2 = 0; i2 < 2; ++i2)
            gl_lds16(Km + (size_t)kb * 128 + (i2 * 256 + tid) * 8,
                     Ks + (i2 * 256 + tid) * 8);
        // stage V 64-chunk every other tile (pre-swizzled image, linear DMA)
        if ((kt & 1) == 0) {
            const unsigned short* src = Vimg + ((size_t)(kc0 + (kt >> 1)) << 13) + tid * 8;
            #pragma unroll
            for (int i2 = 0; i2 < 4; ++i2)
                gl_lds16(src + i2 * 2048, &Vls[(i2 * 256 + tid) * 8]);
        }
        __syncthreads();

        // transposed QK^T: S^T; lane: q = lc, k = (reg&3)+8*(reg>>2)+4*lh
        f32x16 accT;
        #pragma unroll
        for (int r = 0; r < 16; ++r) accT[r] = 0.f;
        #pragma unroll
        for (int d = 0; d < 8; ++d) {
            int slot = d * 2 + lh;
            bf16x8 kf = *(const bf16x8*)(Ks + lc * 128 + ((slot ^ (lc & 15)) << 3));
            accT = __builtin_amdgcn_mfma_f32_32x32x16_bf16(kf, aq[d], accT, 0, 0, 0);
        }

        // P = exp2 (scale pre-folded into Q) -> bf16 pairs pk[t][p]
        unsigned int pk[4][2];
        #pragma unroll
        for (int t = 0; t < 4; ++t)
            #pragma unroll
            for (int p = 0; p < 2; ++p) {
                float e0 = exp2f(accT[t * 4 + 2 * p]);
                float e1 = exp2f(accT[t * 4 + 2 * p + 1]);
                asm("v_cvt_pk_bf16_f32 %0, %1, %2" : "=v"(pk[t][p]) : "v"(e0), "v"(e1));
            }
        // permlane32_swap: (t0,t1) -> A-frag k 0..15; (t2,t3) -> k 16..31 (round-6-verified)
        #pragma unroll
        for (int p = 0; p < 2; ++p) {
            asm volatile("v_permlane32_swap_b32 %0, %1" : "+v"(pk[0][p]), "+v"(pk[1][p]));
            asm volatile("v_permlane32_swap_b32 %0, %1" : "+v"(pk[2][p]), "+v"(pk[3][p]));
        }
        u32x4 u0 = {pk[0][0], pk[0][1], pk[1][0], pk[1][1]};
        u32x4 u1 = {pk[2][0], pk[2][1], pk[3][0], pk[3][1]};
        bf16x8 ap0 = __builtin_bit_cast(bf16x8, u0);
        bf16x8 ap1 = __builtin_bit_cast(bf16x8, u1);

        // PV B-frags from image chunk: g = (kt&1)*4 + khalf*2 + lh
        const int g0 = (kt & 1) * 4 + lh;
        const int g1 = g0 + 2;
        #pragma unroll
        for (int cb = 0; cb < 4; ++cb) {
            int c = cb * 32 + lc;
            bf16x8 v0 = *(const bf16x8*)(Vls + c * 64 + ((g0 ^ (c & 7)) << 3));
            bf16x8 v1 = *(const bf16x8*)(Vls + c * 64 + ((g1 ^ (c & 7)) << 3));
            acco[cb] = __builtin_amdgcn_mfma_f32_32x32x16_bf16(ap0, v0, acco[cb], 0, 0, 0);
            acco[cb] = __builtin_amdgcn_mfma_f32_32x32x16_bf16(ap1, v1, acco[cb], 0, 0, 0);
        }
    }

    #pragma unroll
    for (int cb = 0; cb < 4; ++cb)
        #pragma unroll
        for (int r = 0; r < 16; ++r) {
            int q = (r & 3) + 8 * (r >> 2) + 4 * lh;
            Pout[(size_t)(row0 + q) * CNUM + cb * 32 + lc] = f2b(acco[cb][r]);
        }
}

// ---------------- fused post-attention chain: wo-GEMM + LN2 + MLP (2 GEMMs) + out ----------------
// One 32-row block does the ENTIRE chain; y lives in VGPRs; zh/hh live in LDS images
// (bitwise-identical to the old global round-trips). Bs (32 KB) serially holds
// wo -> w1(half0,half1) -> w2(ph0,ph1), each an L2-resident image, linear DMA.
// GEMM k-orders match the old EPI3/EPI6/EPI8 exactly.
__global__ __launch_bounds__(256, 2) void mlp_fused(
    const unsigned short* __restrict__ parts, const unsigned short* __restrict__ woh,
    const unsigned short* __restrict__ w1h, const unsigned short* __restrict__ w2h,
    const float* __restrict__ bo, const float* __restrict__ b1, const float* __restrict__ b2,
    const float* __restrict__ tres, const float* __restrict__ wln, const float* __restrict__ bln,
    float* __restrict__ out)
{
    __shared__ unsigned short As[32 * 128];      // 8 KB  parts-sum image
    __shared__ unsigned short Bs[128 * 128];     // 32 KB weight tile (reused 5x)
    __shared__ unsigned short zs[32 * 128];      // 8 KB  zh image
    __shared__ unsigned short hs[32 * 256];      // 16 KB hh image
    __shared__ float2 lnred[4 * 32];             // 1 KB
    const int bm = blockIdx.x * 32;
    const int tid = threadIdx.x;
    const int w = tid >> 6, l = tid & 63;
    const int cw = w * 32;
    const int lm = l & 15, lq = l >> 4;
    f32x4 zero = {0.f, 0.f, 0.f, 0.f};

    // ---- A-stage: sum KSPLIT part-slices -> As image; DMA woh -> Bs ----
    #pragma unroll
    for (int i = 0; i < 2; ++i) {
        int cid = i * 256 + tid;
        int r = cid >> 4, c = cid & 15;
        int p = (c ^ r) & 15;
        float s8[8];
        #pragma unroll
        for (int j = 0; j < 8; ++j) s8[j] = 0.f;
        #pragma unroll
        for (int pp = 0; pp < KSPLIT; ++pp) {
            const unsigned short* src = parts + (size_t)pp * ((size_t)MTOT * CNUM)
                                          + (size_t)(bm + r) * 128 + c * 8;
            ushort4 u0 = *(const ushort4*)(src);
            ushort4 u1 = *(const ushort4*)(src + 4);
            s8[0] += b2f(u0.x); s8[1] += b2f(u0.y); s8[2] += b2f(u0.z); s8[3] += b2f(u0.w);
            s8[4] += b2f(u1.x); s8[5] += b2f(u1.y); s8[6] += b2f(u1.z); s8[7] += b2f(u1.w);
        }
        ushort4 o0, o1;
        o0.x = f2b(s8[0]); o0.y = f2b(s8[1]); o0.z = f2b(s8[2]); o0.w = f2b(s8[3]);
        o1.x = f2b(s8[4]); o1.y = f2b(s8[5]); o1.z = f2b(s8[6]); o1.w = f2b(s8[7]);
        *(ushort4*)(As + r * 128 + p * 8) = o0;
        *(ushort4*)(As + r * 128 + p * 8 + 4) = o1;
    }
    #pragma unroll
    for (int i = 0; i < 8; ++i)
        gl_lds16(woh + (i * 256 + tid) * 8, Bs + (i * 256 + tid) * 8);
    __syncthreads();

    // ---- GEMM1: y = attoutΣ @ wo^T + bo + t  (y stays in regs) ----
    f32x4 acc[2][2];
    #pragma unroll
    for (int i = 0; i < 2; ++i) { acc[i][0] = zero; acc[i][1] = zero; }
    #pragma unroll
    for (int ks = 0; ks < 4; ++ks) {
        int c = ks * 4 + lq;
        bf16x8 a[2], bfr[2];
        #pragma unroll
        for (int i = 0; i < 2; ++i) {
            int m = i * 16 + lm;
            a[i] = *(const bf16x8*)(As + m * 128 + (((c ^ m) & 15) << 3));
        }
        #pragma unroll
        for (int j = 0; j < 2; ++j) {
            int n = cw + j * 16 + lm;
            bfr[j] = *(const bf16x8*)(Bs + n * 128 + (((c ^ n) & 15) << 3));
        }
        #pragma unroll
        for (int i = 0; i < 2; ++i)
            #pragma unroll
            for (int j = 0; j < 2; ++j)
                acc[i][j] = __builtin_amdgcn_mfma_f32_16x16x32_bf16(a[i], bfr[j], acc[i][j], 0, 0, 0);
    }
    float vv[2][2][4];
    #pragma unroll
    for (int i = 0; i < 2; ++i) {
        int rowbase = bm + i * 16 + lq * 4;
        #pragma unroll
        for (int j = 0; j < 2; ++j) {
            int col = cw + j * 16 + lm;
            #pragma unroll
            for (int reg = 0; reg < 4; ++reg)
                vv[i][j][reg] = acc[i][j][reg] + bo[col] +
                                tres[(size_t)(rowbase + reg) * 128 + col];
        }
    }
    // LN partials over this wave's 32-col slice
    #pragma unroll
    for (int i = 0; i < 2; ++i)
        #pragma unroll
        for (int reg = 0; reg < 4; ++reg) {
            float s = 0.f, q = 0.f;
            #pragma unroll
            for (int j = 0; j < 2; ++j) {
                float xv = vv[i][j][reg];
                s += xv; q += xv * xv;
            }
            #pragma unroll
            for (int off = 1; off < 16; off <<= 1) {
                s += __shfl_xor(s, off);
                q += __shfl_xor(q, off);
            }
            if (lm == 0) {
                float2 sq2; sq2.x = s; sq2.y = q;
                lnred[w * 32 + i * 16 + lq * 4 + reg] = sq2;
            }
        }
    __syncthreads();                                      // B1: lnred ready; GEMM1 Bs reads done
    // zh -> zs image; issue w1 half0 DMA into Bs
    #pragma unroll
    for (int i = 0; i < 2; ++i) {
        #pragma unroll
        for (int reg = 0; reg < 4; ++reg) {
            int lrow = i * 16 + lq * 4 + reg;
            float sx = 0.f, sq = 0.f;
            #pragma unroll
            for (int g = 0; g < 4; ++g) {
                float2 h = lnred[g * 32 + lrow];
                sx += h.x; sq += h.y;
            }
            float mean = sx * (1.f / 128.f);
            float var  = sq * (1.f / 128.f) - mean * mean;
            float rs2 = rsqrtf(var + EPSLN);
            #pragma unroll
            for (int j = 0; j < 2; ++j) {
                int col = cw + j * 16 + lm;
                zs[lrow * 128 + swz(col, lrow)] =
                    f2b((vv[i][j][reg] - mean) * rs2 * wln[col] + bln[col]);
            }
        }
    }
    #pragma unroll
    for (int i = 0; i < 8; ++i)
        gl_lds16(w1h + (i * 256 + tid) * 8, Bs + (i * 256 + tid) * 8);
    __syncthreads();                                      // B2: zs + Bs(w1 h0) ready

    // ---- GEMM2: hh = gelu(zs @ w1^T + b1), two 128-col halves ----
    #pragma unroll
    for (int h = 0; h < 2; ++h) {
        if (h) {
            __syncthreads();                              // B3: Bs reads done
            #pragma unroll
            for (int i = 0; i < 8; ++i)
                gl_lds16(w1h + 16384 + (i * 256 + tid) * 8, Bs + (i * 256 + tid) * 8);
            __syncthreads();                              // B4
        }
        f32x4 acc2[2][2];
        #pragma unroll
        for (int i = 0; i < 2; ++i) { acc2[i][0] = zero; acc2[i][1] = zero; }
        #pragma unroll
        for (int ks = 0; ks < 4; ++ks) {
            int c = ks * 4 + lq;
            bf16x8 a[2], bfr[2];
            #pragma unroll
            for (int i = 0; i < 2; ++i) {
                int m = i * 16 + lm;
                a[i] = *(const bf16x8*)(zs + m * 128 + (((c ^ m) & 15) << 3));
            }
            #pragma unroll
            for (int j = 0; j < 2; ++j) {
                int n = cw + j * 16 + lm;
                bfr[j] = *(const bf16x8*)(Bs + n * 128 + (((c ^ n) & 15) << 3));
            }
            #pragma unroll
            for (int i = 0; i < 2; ++i)
                #pragma unroll
                for (int j = 0; j < 2; ++j)
                    acc2[i][j] = __builtin_amdgcn_mfma_f32_16x16x32_bf16(a[i], bfr[j], acc2[i][j], 0, 0, 0);
        }
        #pragma unroll
        for (int i = 0; i < 2; ++i) {
            #pragma unroll
            for (int reg = 0; reg < 4; ++reg) {
                int lrow = i * 16 + lq * 4 + reg;
                #pragma unroll
                for (int j = 0; j < 2; ++j) {
                    int col = h * 128 + cw + j * 16 + lm;
                    hs[lrow * 256 + swz(col, lrow)] =
                        f2b(gelu_exact(acc2[i][j][reg] + b1[col]));
                }
            }
        }
    }
    __syncthreads();                                      // B5: hs complete; Bs reads done

    // ---- GEMM3: out = gelu(hs @ w2^T + b2) + y, K=256 in two phases ----
    f32x4 acc3[2][2];
    #pragma unroll
    for (int i = 0; i < 2; ++i) { acc3[i][0] = zero; acc3[i][1] = zero; }
    #pragma unroll
    for (int ph = 0; ph < 2; ++ph) {
        #pragma unroll
        for (int i = 0; i < 8; ++i) {
            int cid = i * 256 + tid;
            int n = cid >> 4, gg = cid & 15;
            gl_lds16(w2h + (size_t)n * 256 + ph * 128 + gg * 8, Bs + cid * 8);
        }
        __syncthreads();                                  // B6/B8
        #pragma unroll
        for (int ks = 0; ks < 4; ++ks) {
            int c_loc = ks * 4 + lq;
            int c_glob = ph * 16 + c_loc;
            bf16x8 a[2], bfr[2];
            #pragma unroll
            for (int i = 0; i < 2; ++i) {
                int m = i * 16 + lm;
                int p = (c_glob & ~15) | ((c_glob ^ m) & 15);
                a[i] = *(const bf16x8*)(hs + m * 256 + p * 8);
            }
            #pragma unroll
            for (int j = 0; j < 2; ++j) {
                int n = cw + j * 16 + lm;
                bfr[j] = *(const bf16x8*)(Bs + n * 128 + (((c_loc ^ n) & 15) << 3));
            }
            #pragma unroll
            for (int i = 0; i < 2; ++i)
                #pragma unroll
                for (int j = 0; j < 2; ++j)
                    acc3[i][j] = __builtin_amdgcn_mfma_f32_16x16x32_bf16(a[i], bfr[j], acc3[i][j], 0, 0, 0);
        }
        if (ph == 0) __syncthreads();                     // B7: Bs reads done before restage
    }

    // epilogue: gelu + y (regs), transposed fp32 store
    #pragma unroll
    for (int i = 0; i < 2; ++i) {
        int rowbase = bm + i * 16 + lq * 4;
        int bb = rowbase >> 12, s = rowbase & 4095;
        #pragma unroll
        for (int j = 0; j < 2; ++j) {
            int col = cw + j * 16 + lm;
            float4 o;
            o.x = gelu_exact(acc3[i][j][0] + b2[col]) + vv[i][j][0];
            o.y = gelu_exact(acc3[i][j][1] + b2[col]) + vv[i][j][1];
            o.z = gelu_exact(acc3[i][j][2] + b2[col]) + vv[i][j][2];
            o.w = gelu_exact(acc3[i][j][3] + b2[col]) + vv[i][j][3];
            *(float4*)(out + ((size_t)(bb * 128 + col)) * 4096 + s) = o;
        }
    }
}

extern "C" void kernel_launch(void* const* d_in, const int* in_sizes, int n_in,
                              void* d_out, int out_size, void* d_ws, size_t ws_size,
                              hipStream_t stream)
{
    (void)in_sizes; (void)n_in; (void)out_size; (void)ws_size;
    const float* x    = (const float*)d_in[0];
    const float* ln1w = (const float*)d_in[1];
    const float* ln1b = (const float*)d_in[2];
    const float* wq   = (const float*)d_in[3];
    const float* bq   = (const float*)d_in[4];
    const float* wk   = (const float*)d_in[5];
    const float* bk   = (const float*)d_in[6];
    const float* wv   = (const float*)d_in[7];
    const float* bv   = (const float*)d_in[8];
    const float* wo   = (const float*)d_in[9];
    const float* bo   = (const float*)d_in[10];
    const float* ln2w = (const float*)d_in[11];
    const float* ln2b = (const float*)d_in[12];
    const float* w1   = (const float*)d_in[13];
    const float* b1   = (const float*)d_in[14];
    const float* w2   = (const float*)d_in[15];
    const float* b2   = (const float*)d_in[16];
    float* out = (float*)d_out;

    float* ws = (float*)d_ws;
    const size_t NSC = (size_t)MTOT * CNUM;            // 2,097,152
    float* t      = ws;
    float* y      = t + NSC;                           // (unused, kept for layout)
    float* psum   = y + NSC;                           // [QSPLIT][B][S]
    unsigned short* parts = (unsigned short*)(psum + (size_t)QSPLIT * BATCH * S); // [KSPLIT][B][S][C]
    unsigned short* xlh = parts + (size_t)8 * NSC;     // keep layout headroom (KSPLIT<=8)
    unsigned short* qh  = xlh + NSC;
    unsigned short* kh  = qh + NSC;                    // V image must follow kh (EPI7 contiguity)
    unsigned short* Vt  = kh + NSC;                    // pre-swizzled V image
    unsigned short* zh  = Vt + NSC;                    // (unused)
    unsigned short* hh  = zh + NSC;                    // (unused)
    unsigned short* wqkvh = hh + (size_t)MTOT * 256;
    unsigned short* woh = wqkvh + 3 * 16384;
    unsigned short* w1h = woh + 16384;                 // [256][128]
    unsigned short* w2h = w1h + 32768;                 // [128][256]
    float* bqkv = (float*)(w2h + 32768);               // [384]

    ln1_transpose<<<dim3(S / 64, BATCH), 256, 0, stream>>>(x, ln1w, ln1b, xlh, t);
    convw<<<dim3(128, 7), 256, 0, stream>>>(wq, wk, wv, wo, w1, w2, bq, bk, bv,
                                            wqkvh, woh, w1h, w2h, bqkv);

    // QKV: one launch, z = {q(scaled image), k(image), v(chunk image)} — BM=32, 1536 blocks
    gemm_mfma<128, 7, 32><<<dim3(1, MTOT / 32, 3), 256, 0, stream>>>(
        xlh, wqkvh, bqkv, nullptr, qh, nullptr, nullptr, nullptr, 128);

    colsum<<<dim3(S / 128, QSPLIT, BATCH), 256, 0, stream>>>(qh, kh, psum);
    vscale<<<dim3(CNUM * S / 4 / 256, 1, BATCH), 256, 0, stream>>>(Vt, psum);
    fused_attnv<<<dim3(KSPLIT, S / 128, BATCH), 256, 0, stream>>>(qh, kh, Vt, parts);

    // full post-attention chain in one kernel — 512 blocks
    mlp_fused<<<MTOT / 32, 256, 0, stream>>>(
        parts, woh, w1h, w2h, bo, b1, b2, t, ln2w, ln2b, out);
}